// Round 5
// baseline (205.828 us; speedup 1.0000x reference)
//
#include <hip/hip_runtime.h>

// YOLO loss. B=32, H=W=32, A=9, C=80, T=50, NET=512.
// 4 lanes per cell; lane s owns floats [16j+4s .. 16j+4s+3] of its cell via
// 16-B loads (unaligned-capable). Block = 256 threads = 64 cells, one batch b.
// Per-wave IoU tables in LDS (no __syncthreads anywhere). Grid = 4608 blocks.

constexpr int NT = 50;
typedef __attribute__((ext_vector_type(4))) float f4;

__global__ __launch_bounds__(256) void yolo_loss_kernel(
    const float* __restrict__ y_pred,     // (B,H,W,A,85) flat
    const float* __restrict__ y_true,     // (B,H,W,A,85)
    const float* __restrict__ true_boxes, // (B,50,4)
    const float* __restrict__ anchors,    // (9,2)
    float* __restrict__ out)              // (B,)
{
    __shared__ f4    s_box[4][NT];     // {minx, maxx, miny, maxy}, per wave
    __shared__ float s_area[4][NT];

    const int tid  = threadIdx.x;
    const int lane = tid & 63;
    const int wid  = tid >> 6;
    const int s    = lane & 3;         // slice within cell group
    const int gb   = lane & ~3;        // group base lane in wave

    const int cell0 = blockIdx.x * 64;         // 64 cells per block, same b
    const int b     = cell0 / 9216;            // 144 blocks per batch image

    const int cell  = cell0 + (tid >> 2);
    const int local = cell - b * 9216;
    const int a = local % 9;
    const int w = (local / 9) % 32;
    const int h = local / 288;

    const size_t cbase = (size_t)cell * 85;
    const float* cp = y_pred + cbase;
    const float* ct = y_true + cbase;

    // ---- issue all main loads up front (independent, 16B each) ----
    f4 pv[5], tv[5];
    #pragma unroll
    for (int j = 0; j < 5; ++j) {
        __builtin_memcpy(&pv[j], cp + 16 * j + 4 * s, 16);
        __builtin_memcpy(&tv[j], ct + 16 * j + 4 * s, 16);
    }
    f4 pt = {0.f, 0.f, 0.f, 0.f}, tt = {0.f, 0.f, 0.f, 0.f};
    float p84 = 0.f, t84 = 0.f;
    if (s == 0) {                               // floats 80..83
        __builtin_memcpy(&pt, cp + 80, 16);
        __builtin_memcpy(&tt, ct + 80, 16);
    }
    if (s == 1) { p84 = cp[84]; t84 = ct[84]; } // float 84

    const float aw = anchors[a * 2 + 0];
    const float ah = anchors[a * 2 + 1];

    // ---- per-wave IoU table (no block barrier needed) ----
    if (lane < NT) {
        f4 tb;
        __builtin_memcpy(&tb, true_boxes + ((size_t)b * NT + lane) * 4, 16);
        const float tx = tb[0] * (1.0f / 32.0f);
        const float ty = tb[1] * (1.0f / 32.0f);
        const float tw = tb[2] * (1.0f / 512.0f);
        const float th = tb[3] * (1.0f / 512.0f);
        f4 e;
        e[0] = tx - tw * 0.5f;  e[1] = tx + tw * 0.5f;
        e[2] = ty - th * 0.5f;  e[3] = ty + th * 0.5f;
        s_box[wid][lane]  = e;
        s_area[wid][lane] = tw * th;
    }
    asm volatile("s_waitcnt lgkmcnt(0)" ::: "memory");  // wave-local LDS fence

    // ---- broadcast box fields (f0..f4) across the 4-lane group ----
    const float p0 = __shfl(pv[0][0], gb + 0);
    const float p1 = __shfl(pv[0][1], gb + 0);
    const float p2 = __shfl(pv[0][2], gb + 0);
    const float p3 = __shfl(pv[0][3], gb + 0);
    const float p4 = __shfl(pv[0][0], gb + 1);
    const float t0 = __shfl(tv[0][0], gb + 0);
    const float t1 = __shfl(tv[0][1], gb + 0);
    const float t2 = __shfl(tv[0][2], gb + 0);
    const float t3 = __shfl(tv[0][3], gb + 0);
    const float t4 = __shfl(tv[0][0], gb + 1);

    // ---- per-cell geometry (redundant on 4 lanes — cheap) ----
    const float sig0  = 1.0f / (1.0f + __expf(-p0));
    const float sig1  = 1.0f / (1.0f + __expf(-p1));
    const float predx = (float)w + sig0;
    const float predy = (float)h + sig1;
    const float pconf = 1.0f / (1.0f + __expf(-p4));

    const float px = predx * (1.0f / 32.0f);
    const float py = predy * (1.0f / 32.0f);
    const float pw = __expf(p2) * aw * (1.0f / 512.0f);
    const float ph = __expf(p3) * ah * (1.0f / 512.0f);
    const float pminx = px - pw * 0.5f, pmaxx = px + pw * 0.5f;
    const float pminy = py - ph * 0.5f, pmaxy = py + ph * 0.5f;
    const float parea = pw * ph;

    // ---- IoU ignore flag: boxes 4i+s per lane; OR across group later ----
    // best_iou >= 0.5  <=>  exists t: 2*inter >= union (union > 0 always)
    int ig = 0;
    #pragma unroll
    for (int i = 0; i < 13; ++i) {
        const int box = 4 * i + s;
        if (box < NT) {
            const f4 e = s_box[wid][box];
            float iw = fminf(pmaxx, e[1]) - fmaxf(pminx, e[0]);
            float ih = fminf(pmaxy, e[3]) - fmaxf(pminy, e[2]);
            iw = fmaxf(iw, 0.0f);
            ih = fmaxf(ih, 0.0f);
            const float inter = iw * ih;
            const float uni   = parea + s_area[wid][box] - inter;
            ig |= (2.0f * inter >= uni) ? 1 : 0;
        }
    }

    // ---- classes pass 1: argmax(true) carrying pred, and max(pred) ----
    float tmax = -1e30f, p_at = 0.0f, pmax = -1e30f;
    int   tidx = 1 << 20;
    #pragma unroll
    for (int j = 0; j < 5; ++j) {
        #pragma unroll
        for (int e = 0; e < 4; ++e) {
            const float tc = tv[j][e];
            const float pc = pv[j][e];
            const bool cls = (j > 0) || (4 * s + e >= 5);
            const float tcm = cls ? tc : -1e30f;
            const bool upd = tcm > tmax;           // strict >: first occurrence
            if (upd) { tmax = tcm; p_at = pc; tidx = 16 * j + 4 * s + e; }
            pmax = fmaxf(pmax, cls ? pc : -1e30f);
        }
    }
    #pragma unroll
    for (int e = 0; e < 4; ++e) {                  // tail f80..83 (s==0 only)
        const float tcm = (s == 0) ? tt[e] : -1e30f;
        if (tcm > tmax) { tmax = tcm; p_at = pt[e]; tidx = 80 + e; }
        pmax = fmaxf(pmax, (s == 0) ? pt[e] : -1e30f);
    }
    {                                              // tail f84 (s==1 only)
        const float tcm = (s == 1) ? t84 : -1e30f;
        if (tcm > tmax) { tmax = tcm; p_at = p84; tidx = 84; }
        pmax = fmaxf(pmax, (s == 1) ? p84 : -1e30f);
    }

    // combine across the 4 lanes of the group
    #pragma unroll
    for (int d = 1; d <= 2; d <<= 1) {
        const float ot = __shfl_xor(tmax, d);
        const float op = __shfl_xor(p_at, d);
        const int   oi = __shfl_xor(tidx, d);
        const bool upd = (ot > tmax) || (ot == tmax && oi < tidx);
        tmax = upd ? ot : tmax;
        p_at = upd ? op : p_at;
        tidx = upd ? oi : tidx;
        pmax = fmaxf(pmax, __shfl_xor(pmax, d));
        ig  |= __shfl_xor(ig, d);
    }

    // ---- classes pass 2: sum exp(pred - pmax), 4 accumulator streams ----
    f4 acc = {0.f, 0.f, 0.f, 0.f};
    #pragma unroll
    for (int j = 0; j < 5; ++j) {
        #pragma unroll
        for (int e = 0; e < 4; ++e) {
            const bool cls = (j > 0) || (4 * s + e >= 5);
            const float v = __expf(pv[j][e] - pmax);
            acc[e] += cls ? v : 0.0f;
        }
    }
    #pragma unroll
    for (int e = 0; e < 4; ++e) {
        const float v = __expf(pt[e] - pmax);
        acc[e] += (s == 0) ? v : 0.0f;
    }
    {
        const float v = __expf(p84 - pmax);
        acc[0] += (s == 1) ? v : 0.0f;
    }
    float sum = (acc[0] + acc[1]) + (acc[2] + acc[3]);
    sum += __shfl_xor(sum, 1);
    sum += __shfl_xor(sum, 2);
    const float ce = (pmax + __logf(sum)) - p_at;

    // ---- deltas ----
    const float om  = t4;
    const float ew  = __expf(t2) * aw * (1.0f / 512.0f);
    const float eh  = __expf(t3) * ah * (1.0f / 512.0f);
    const float whs = 2.0f - ew * eh;

    const float xyd0 = om * (predx - t0) * whs;
    const float xyd1 = om * (predy - t1) * whs;
    const float whd0 = om * (p2 - t2) * whs;
    const float whd1 = om * (p3 - t3) * whs;
    const float cd   = om * (pconf - t4) * 5.0f + (1.0f - om) * (ig ? 0.0f : pconf);

    float partial = xyd0 * xyd0 + xyd1 * xyd1 + whd0 * whd0 + whd1 * whd1 +
                    cd * cd + om * ce;

    // ---- wave-level sum of the 16 group leaders; one atomic per wave ----
    partial = (s == 0) ? partial : 0.0f;
    partial += __shfl_xor(partial, 4);
    partial += __shfl_xor(partial, 8);
    partial += __shfl_xor(partial, 16);
    partial += __shfl_xor(partial, 32);
    if (lane == 0)
        atomicAdd(&out[b], partial);
}

extern "C" void kernel_launch(void* const* d_in, const int* in_sizes, int n_in,
                              void* d_out, int out_size, void* d_ws, size_t ws_size,
                              hipStream_t stream) {
    // setup_inputs order: input_image (unused), y_pred, y_true, true_boxes, anchors
    const float* y_pred     = (const float*)d_in[1];
    const float* y_true     = (const float*)d_in[2];
    const float* true_boxes = (const float*)d_in[3];
    const float* anchors    = (const float*)d_in[4];
    float* out = (float*)d_out;

    hipMemsetAsync(d_out, 0, (size_t)out_size * sizeof(float), stream);

    dim3 grid(294912 / 64);   // 4608 blocks, 64 cells each
    yolo_loss_kernel<<<grid, 256, 0, stream>>>(y_pred, y_true, true_boxes, anchors, out);
}